// Round 14
// baseline (253.359 us; speedup 1.0000x reference)
//
#include <hip/hip_runtime.h>
#include <math.h>

#define LRELU 0.2f
#define CBSH 7                 // 128 dsts per coarse pairs-bucket
#define CBSZ (1 << CBSH)
#define CAPC 4608              // padded coarse bucket capacity (avg ~4092, +8 sigma)
#define GDS 32                 // dsts per gather block (quarter of coarse bucket)
#define CH 8192                // edges per binscat block
#define GB 10                  // gather batch depth (loads in flight per lane)
#define CAPG 1408              // colT capacity per gather block (avg ~1024, +12 sigma)

typedef __attribute__((ext_vector_type(8))) short bf16x8;
typedef __attribute__((ext_vector_type(4))) float f32x4;

static __device__ __forceinline__ float bf2f(unsigned int u16) {
    union { unsigned int i; float f; } c; c.i = u16 << 16; return c.f;
}
static __device__ __forceinline__ unsigned short f2bf(float f) {
    union { float f; unsigned int i; } c; c.f = f;
    unsigned int x = c.i;
    return (unsigned short)((x + 0x7fffu + ((x >> 16) & 1u)) >> 16);  // RNE
}

// ---- prep: weight cvt + sentinels + w2 projections + padded-bucket init ----

__global__ __launch_bounds__(256) void k_prep(const float* __restrict__ W1,
                                              const float* __restrict__ W2,
                                              const float* __restrict__ as2in,
                                              const float* __restrict__ ad2in,
                                              unsigned short* __restrict__ Wt1,
                                              unsigned short* __restrict__ Wt2,
                                              unsigned short* __restrict__ h1b,
                                              unsigned short* __restrict__ gb,
                                              float* __restrict__ w2s,
                                              float* __restrict__ w2d,
                                              int* __restrict__ bcur,
                                              int N, int NBC) {
    int idx = blockIdx.x * 256 + threadIdx.x;
    if (idx < 16384) {
        int n = idx >> 8, k = idx & 255;
        Wt1[idx] = f2bf(W1[k * 64 + n]);
    } else if (idx < 16384 + 4096) {
        int j = idx - 16384;
        int n = j >> 6, k = j & 63;
        Wt2[j] = f2bf(W2[k * 64 + n]);
    } else if (idx >= 20480 && idx < 20544) {
        h1b[(size_t)N * 64 + (idx - 20480)] = 0;           // Hb sentinel row = 0
    } else if (idx >= 20544 && idx < 20608) {
        gb[(size_t)N * 64 + (idx - 20544)] = 0;            // Gb sentinel row = 0
    } else if (idx >= 20608 && idx < 20672) {
        int c = idx - 20608;
        float s = 0.f;
#pragma unroll
        for (int n = 0; n < 64; ++n) s += W2[c * 64 + n] * as2in[n];
        w2s[c] = s;                                        // W2 @ att_src2
    } else if (idx >= 20672 && idx < 20736) {
        int c = idx - 20672;
        float s = 0.f;
#pragma unroll
        for (int n = 0; n < 64; ++n) s += W2[c * 64 + n] * ad2in[n];
        w2d[c] = s;                                        // W2 @ att_dst2
    } else if (idx >= 20736 && idx < 20736 + NBC) {
        int b = idx - 20736;
        bcur[b] = b * CAPC;                                // padded bucket base
    }
}

// ---- mid: role-split fused kernel: binscat chunks (lds_d staged) + gemm1 ----
// lds_d overlays the gemm role's Xl buffer (both exactly 32 KB).
// Coarse 128-dst buckets -> ~21-edge runs per chunk -> near-line-sized writes.

__global__ __launch_bounds__(256) void k_mid(const int* __restrict__ src,
                                             const int* __restrict__ dstArr,
                                             int E, int NBC,
                                             int* __restrict__ bcur,
                                             unsigned* __restrict__ pairs,
                                             const float* __restrict__ X,
                                             const unsigned short* __restrict__ Wt,
                                             const float* __restrict__ attd,
                                             int N, unsigned short* __restrict__ Hb,
                                             float* __restrict__ adst,
                                             int nchunk) {
    __shared__ short Xl[64 * 256];          // 32 KB; binscat overlays lds_d here
    __shared__ int cnt2[512];
    int t = threadIdx.x;
    if ((int)blockIdx.x < nchunk) {
        int* lds_d = (int*)Xl;              // CH ints = 32 KB, exact overlay
        int e0 = blockIdx.x * CH;
        int e1 = e0 + CH; if (e1 > E) e1 = E;
        int n = e1 - e0;
        for (int b = t; b < 512; b += 256) cnt2[b] = 0;
        __syncthreads();
        for (int i = t; i < n; i += 256) {
            int d = dstArr[e0 + i];
            lds_d[i] = d;
            atomicAdd(&cnt2[d >> CBSH], 1);
        }
        __syncthreads();
        for (int b = t; b < NBC; b += 256) {
            int c = cnt2[b];
            cnt2[b] = c ? atomicAdd(&bcur[b], c) : 0;
        }
        __syncthreads();
        for (int i = t; i < n; i += 256) {
            int d = lds_d[i];
            int p = atomicAdd(&cnt2[d >> CBSH], 1);
            pairs[p] = ((unsigned)src[e0 + i] << CBSH) | (unsigned)(d & (CBSZ - 1));
        }
        return;
    }
    // -------- gemm1 role --------
    int bx = (int)blockIdx.x - nchunk;
    int l = t & 63, w = t >> 6;
    int rblk = bx * 64;

    int half = l >> 5;
    int c8 = (l & 31) * 8;
#pragma unroll
    for (int i = 0; i < 8; ++i) {
        int rl = w * 16 + i * 2 + half;
        int row = rblk + rl;
        float4 x0 = {0.f, 0.f, 0.f, 0.f}, x1 = {0.f, 0.f, 0.f, 0.f};
        if (row < N) {
            x0 = *reinterpret_cast<const float4*>(X + (size_t)row * 256 + c8);
            x1 = *reinterpret_cast<const float4*>(X + (size_t)row * 256 + c8 + 4);
        }
        bf16x8 p;
        p[0] = (short)f2bf(x0.x); p[1] = (short)f2bf(x0.y);
        p[2] = (short)f2bf(x0.z); p[3] = (short)f2bf(x0.w);
        p[4] = (short)f2bf(x1.x); p[5] = (short)f2bf(x1.y);
        p[6] = (short)f2bf(x1.z); p[7] = (short)f2bf(x1.w);
        int g = (l & 31) ^ (rl & 7);
        *reinterpret_cast<bf16x8*>(&Xl[rl * 256 + g * 8]) = p;
    }
    __syncthreads();

    int m = l & 15, quad = l >> 4;
    int rl = w * 16 + m;
    f32x4 acc0 = {0.f, 0.f, 0.f, 0.f}, acc1 = acc0, acc2 = acc0, acc3 = acc0;
#pragma unroll
    for (int tt = 0; tt < 8; ++tt) {
        int g = (tt * 4 + quad) ^ (m & 7);
        bf16x8 a = *reinterpret_cast<const bf16x8*>(&Xl[rl * 256 + g * 8]);
        int kk = tt * 32 + quad * 8;
        bf16x8 b0 = *reinterpret_cast<const bf16x8*>(&Wt[(0 * 16 + m) * 256 + kk]);
        bf16x8 b1 = *reinterpret_cast<const bf16x8*>(&Wt[(1 * 16 + m) * 256 + kk]);
        bf16x8 b2 = *reinterpret_cast<const bf16x8*>(&Wt[(2 * 16 + m) * 256 + kk]);
        bf16x8 b3 = *reinterpret_cast<const bf16x8*>(&Wt[(3 * 16 + m) * 256 + kk]);
        acc0 = __builtin_amdgcn_mfma_f32_16x16x32_bf16(a, b0, acc0, 0, 0, 0);
        acc1 = __builtin_amdgcn_mfma_f32_16x16x32_bf16(a, b1, acc1, 0, 0, 0);
        acc2 = __builtin_amdgcn_mfma_f32_16x16x32_bf16(a, b2, acc2, 0, 0, 0);
        acc3 = __builtin_amdgcn_mfma_f32_16x16x32_bf16(a, b3, acc3, 0, 0, 0);
    }

    int r0 = rblk + w * 16;
    f32x4 accs[4] = {acc0, acc1, acc2, acc3};
#pragma unroll
    for (int nt = 0; nt < 4; ++nt) {
        int cn = nt * 16 + m;
        float av_d = attd[cn];
#pragma unroll
        for (int r = 0; r < 4; ++r) {
            int row = r0 + quad * 4 + r;
            float hv = accs[nt][r];
            if (row < N) Hb[(size_t)row * 64 + cn] = f2bf(hv);
            float vd = hv * av_d;
            vd += __shfl_xor(vd, 1, 64); vd += __shfl_xor(vd, 2, 64); vd += __shfl_xor(vd, 4, 64);
            if ((m & 7) == 0 && row < N) {
                adst[row * 8 + (cn >> 3)] = vd;
            }
        }
    }
}

// --- gather1 + quarter-filtered in-LDS sort + layer-2 GEMM fused.
//     Block b covers dsts [b*32, b*32+32) = quarter (b&3) of coarse bucket b>>2.
//     Two filtered passes over the coarse bucket (global, L2-hot):
//     histogram matching pairs -> 32-bin scan -> scatter into colT. ---

__global__ __launch_bounds__(256) void k_gather1f(const int* __restrict__ bcur,
                                                  const unsigned* __restrict__ pairs,
                                                  const uint4* __restrict__ Hb8,
                                                  const float* __restrict__ adst,
                                                  const float* __restrict__ attS,
                                                  const float* __restrict__ bias,
                                                  const unsigned short* __restrict__ Wt2,
                                                  const float* __restrict__ w2d,
                                                  int N,
                                                  unsigned short* __restrict__ Gb,
                                                  float* __restrict__ ad2) {
    __shared__ int colT[CAPG];
    __shared__ int cntS[GDS];
    __shared__ int baseS[GDS];
    __shared__ int curS[GDS];
    __shared__ short h2l[32 * 64];
    int t = threadIdx.x;
    int gid = t >> 3, sub = t & 7;
    int b = blockIdx.x;
    int d0 = b * GDS;
    int d = d0 + gid;
    int dok = (d < N);
    int dc = dok ? d : d0;
    float adv = dok ? adst[dc * 8 + sub] : 0.f;
    float aS[8];
#pragma unroll
    for (int c = 0; c < 8; ++c) aS[c] = attS[sub * 8 + c];

    // ---- quarter-filtered counting sort (from coarse bucket b>>2) ----
    int cb = b >> 2;
    unsigned qt = (unsigned)(b & 3);
    int cbase = cb * CAPC;
    int n = bcur[cb] - cbase;
    if (t < GDS) cntS[t] = 0;
    __syncthreads();
    for (int i = t; i < n; i += 256) {
        unsigned pk = pairs[cbase + i];
        if (((pk >> 5) & 3u) == qt) atomicAdd(&cntS[pk & (GDS - 1)], 1);
    }
    __syncthreads();
    if (t < 64) {
        int v = (t < GDS) ? cntS[t] : 0;
        int inc = v;
#pragma unroll
        for (int off = 1; off < GDS; off <<= 1) {
            int q = __shfl_up(inc, off, 64);
            if (t >= off) inc += q;
        }
        if (t < GDS) { baseS[t] = inc - v; curS[t] = inc - v; }
    }
    __syncthreads();
    for (int i = t; i < n; i += 256) {
        unsigned pk = pairs[cbase + i];
        if (((pk >> 5) & 3u) == qt) {
            int p = atomicAdd(&curS[pk & (GDS - 1)], 1);
            colT[p] = (int)(pk >> CBSH);
        }
    }
    __syncthreads();

    int lo = baseS[gid];
    int hi = lo + cntS[gid];

    float acc[8] = {0.f, 0.f, 0.f, 0.f, 0.f, 0.f, 0.f, 0.f};
    float denom = 0.f;
    for (int u = lo; u < hi; u += GB) {
        uint4 hv8[GB];
#pragma unroll
        for (int q = 0; q < GB; ++q) {
            int uu = u + q;
            int s = (uu < hi) ? colT[uu] : N;   // sentinel row = 0
            hv8[q] = Hb8[(size_t)s * 8 + sub];
        }
        __builtin_amdgcn_sched_barrier(0);
#pragma unroll
        for (int q = 0; q < GB; ++q) {
            uint4 hv = hv8[q];
            float f0 = bf2f(hv.x & 0xffffu), f1 = bf2f(hv.x >> 16);
            float f2 = bf2f(hv.y & 0xffffu), f3 = bf2f(hv.y >> 16);
            float f4 = bf2f(hv.z & 0xffffu), f5 = bf2f(hv.z >> 16);
            float f6 = bf2f(hv.w & 0xffffu), f7 = bf2f(hv.w >> 16);
            float ps = f0 * aS[0];
            ps = fmaf(f1, aS[1], ps); ps = fmaf(f2, aS[2], ps);
            ps = fmaf(f3, aS[3], ps); ps = fmaf(f4, aS[4], ps);
            ps = fmaf(f5, aS[5], ps); ps = fmaf(f6, aS[6], ps);
            ps = fmaf(f7, aS[7], ps);
            float e = ps + adv;
            e = (e > 0.f) ? e : LRELU * e;
            float wgt = ((u + q) < hi) ? __expf(e) : 0.f;
            denom += wgt;
            acc[0] = fmaf(wgt, f0, acc[0]); acc[1] = fmaf(wgt, f1, acc[1]);
            acc[2] = fmaf(wgt, f2, acc[2]); acc[3] = fmaf(wgt, f3, acc[3]);
            acc[4] = fmaf(wgt, f4, acc[4]); acc[5] = fmaf(wgt, f5, acc[5]);
            acc[6] = fmaf(wgt, f6, acc[6]); acc[7] = fmaf(wgt, f7, acc[7]);
        }
    }

    // h2 = elu(agg/denom + bias1); ad2 = h2 . (W2@att_dst2) group-reduced
    float invd = 1.f / (denom + 1e-16f);
    float v[8];
#pragma unroll
    for (int c = 0; c < 8; ++c) {
        float x = fmaf(acc[c], invd, bias[sub * 8 + c]);
        v[c] = (x > 0.f) ? x : expm1f(x);
    }
    float vd = 0.f;
#pragma unroll
    for (int c = 0; c < 8; ++c) vd = fmaf(v[c], w2d[sub * 8 + c], vd);
    vd += __shfl_xor(vd, 1, 64); vd += __shfl_xor(vd, 2, 64); vd += __shfl_xor(vd, 4, 64);
    if (dok && sub == 0) ad2[d] = vd;

    // stage h2 bf16 into LDS, octet XOR-swizzled (row r, octet o at o^(r&7))
    bf16x8 p;
#pragma unroll
    for (int c = 0; c < 8; ++c) p[c] = (short)f2bf(v[c]);
    *reinterpret_cast<bf16x8*>(&h2l[gid * 64 + (sub ^ (gid & 7)) * 8]) = p;
    __syncthreads();

    // 32x64 = h2l(32x64) @ W2(64x64), 16x16x32 MFMA, 4 waves x (1 Mtile x 2 Ntiles)
    int l = t & 63, w = t >> 6;
    int m = l & 15, quad = l >> 4;
    int mt = w & 1;
    int ntb = (w >> 1) * 2;
    int r = mt * 16 + m;
    f32x4 g0 = {0.f, 0.f, 0.f, 0.f}, g1 = g0;
#pragma unroll
    for (int tt = 0; tt < 2; ++tt) {
        bf16x8 a = *reinterpret_cast<const bf16x8*>(
            &h2l[r * 64 + ((tt * 4 + quad) ^ (r & 7)) * 8]);
        int kk = tt * 32 + quad * 8;
        bf16x8 b0 = *reinterpret_cast<const bf16x8*>(&Wt2[((ntb + 0) * 16 + m) * 64 + kk]);
        bf16x8 b1 = *reinterpret_cast<const bf16x8*>(&Wt2[((ntb + 1) * 16 + m) * 64 + kk]);
        g0 = __builtin_amdgcn_mfma_f32_16x16x32_bf16(a, b0, g0, 0, 0, 0);
        g1 = __builtin_amdgcn_mfma_f32_16x16x32_bf16(a, b1, g1, 0, 0, 0);
    }
    f32x4 gs[2] = {g0, g1};
#pragma unroll
    for (int nt = 0; nt < 2; ++nt) {
        int cn = (ntb + nt) * 16 + m;
#pragma unroll
        for (int rr = 0; rr < 4; ++rr) {
            int dr = d0 + mt * 16 + quad * 4 + rr;
            if (dr < N) Gb[(size_t)dr * 64 + cn] = f2bf(gs[nt][rr]);
        }
    }
}

// --- gather2: same quarter-filtered sort; asrc2 derived from the Gb row ---

__global__ __launch_bounds__(256) void k_gather2(const int* __restrict__ bcur,
                                                 const unsigned* __restrict__ pairs,
                                                 const uint4* __restrict__ Gb8,
                                                 const float* __restrict__ adst,
                                                 const float* __restrict__ w2s,
                                                 const float* __restrict__ bias,
                                                 int N,
                                                 float* __restrict__ out) {
    __shared__ int colT[CAPG];
    __shared__ int cntS[GDS];
    __shared__ int baseS[GDS];
    __shared__ int curS[GDS];
    int t = threadIdx.x;
    int gid = t >> 3, sub = t & 7;
    int b = blockIdx.x;
    int d0 = b * GDS;
    int d = d0 + gid;
    int dok = (d < N);
    int dc = dok ? d : d0;
    float adv = dok ? adst[dc] : 0.f;
    float wS[8];
#pragma unroll
    for (int c = 0; c < 8; ++c) wS[c] = w2s[sub * 8 + c];

    int cb = b >> 2;
    unsigned qt = (unsigned)(b & 3);
    int cbase = cb * CAPC;
    int n = bcur[cb] - cbase;
    if (t < GDS) cntS[t] = 0;
    __syncthreads();
    for (int i = t; i < n; i += 256) {
        unsigned pk = pairs[cbase + i];
        if (((pk >> 5) & 3u) == qt) atomicAdd(&cntS[pk & (GDS - 1)], 1);
    }
    __syncthreads();
    if (t < 64) {
        int v = (t < GDS) ? cntS[t] : 0;
        int inc = v;
#pragma unroll
        for (int off = 1; off < GDS; off <<= 1) {
            int q = __shfl_up(inc, off, 64);
            if (t >= off) inc += q;
        }
        if (t < GDS) { baseS[t] = inc - v; curS[t] = inc - v; }
    }
    __syncthreads();
    for (int i = t; i < n; i += 256) {
        unsigned pk = pairs[cbase + i];
        if (((pk >> 5) & 3u) == qt) {
            int p = atomicAdd(&curS[pk & (GDS - 1)], 1);
            colT[p] = (int)(pk >> CBSH);
        }
    }
    __syncthreads();

    int lo = baseS[gid];
    int hi = lo + cntS[gid];

    float acc[8] = {0.f, 0.f, 0.f, 0.f, 0.f, 0.f, 0.f, 0.f};
    float denom = 0.f;
    for (int u = lo; u < hi; u += GB) {
        uint4 hv8[GB];
#pragma unroll
        for (int q = 0; q < GB; ++q) {
            int uu = u + q;
            int s = (uu < hi) ? colT[uu] : N;
            hv8[q] = Gb8[(size_t)s * 8 + sub];
        }
        __builtin_amdgcn_sched_barrier(0);
#pragma unroll
        for (int q = 0; q < GB; ++q) {
            uint4 hv = hv8[q];
            float f0 = bf2f(hv.x & 0xffffu), f1 = bf2f(hv.x >> 16);
            float f2 = bf2f(hv.y & 0xffffu), f3 = bf2f(hv.y >> 16);
            float f4 = bf2f(hv.z & 0xffffu), f5 = bf2f(hv.z >> 16);
            float f6 = bf2f(hv.w & 0xffffu), f7 = bf2f(hv.w >> 16);
            float ps = f0 * wS[0];
            ps = fmaf(f1, wS[1], ps); ps = fmaf(f2, wS[2], ps);
            ps = fmaf(f3, wS[3], ps); ps = fmaf(f4, wS[4], ps);
            ps = fmaf(f5, wS[5], ps); ps = fmaf(f6, wS[6], ps);
            ps = fmaf(f7, wS[7], ps);
            ps += __shfl_xor(ps, 1, 64);
            ps += __shfl_xor(ps, 2, 64);
            ps += __shfl_xor(ps, 4, 64);
            float e = ps + adv;
            e = (e > 0.f) ? e : LRELU * e;
            float wgt = ((u + q) < hi) ? __expf(e) : 0.f;
            denom += wgt;
            acc[0] = fmaf(wgt, f0, acc[0]); acc[1] = fmaf(wgt, f1, acc[1]);
            acc[2] = fmaf(wgt, f2, acc[2]); acc[3] = fmaf(wgt, f3, acc[3]);
            acc[4] = fmaf(wgt, f4, acc[4]); acc[5] = fmaf(wgt, f5, acc[5]);
            acc[6] = fmaf(wgt, f6, acc[6]); acc[7] = fmaf(wgt, f7, acc[7]);
        }
    }
    float invd = 1.f / (denom + 1e-16f);
    float v[8];
#pragma unroll
    for (int c = 0; c < 8; ++c) v[c] = fmaf(acc[c], invd, bias[sub * 8 + c]);
    // log_softmax over the 8-lane group (64 channels per dst)
    float m = v[0];
#pragma unroll
    for (int c = 1; c < 8; ++c) m = fmaxf(m, v[c]);
    m = fmaxf(m, __shfl_xor(m, 1, 64));
    m = fmaxf(m, __shfl_xor(m, 2, 64));
    m = fmaxf(m, __shfl_xor(m, 4, 64));
    float se = 0.f;
#pragma unroll
    for (int c = 0; c < 8; ++c) se += __expf(v[c] - m);
    se += __shfl_xor(se, 1, 64);
    se += __shfl_xor(se, 2, 64);
    se += __shfl_xor(se, 4, 64);
    float ls = m + __logf(se);
    if (dok) {
        float4 o0, o1;
        o0.x = v[0] - ls; o0.y = v[1] - ls; o0.z = v[2] - ls; o0.w = v[3] - ls;
        o1.x = v[4] - ls; o1.y = v[5] - ls; o1.z = v[6] - ls; o1.w = v[7] - ls;
        *reinterpret_cast<float4*>(&out[(size_t)d * 64 + sub * 8]) = o0;
        *reinterpret_cast<float4*>(&out[(size_t)d * 64 + sub * 8 + 4]) = o1;
    }
}

// ---------------- launch ----------------

extern "C" void kernel_launch(void* const* d_in, const int* in_sizes, int n_in,
                              void* d_out, int out_size, void* d_ws, size_t ws_size,
                              hipStream_t stream) {
    const float* x   = (const float*)d_in[0];
    const int*   ei  = (const int*)d_in[1];
    const float* W1  = (const float*)d_in[2];
    const float* as1 = (const float*)d_in[3];
    const float* ad1 = (const float*)d_in[4];
    const float* b1  = (const float*)d_in[5];
    const float* W2  = (const float*)d_in[6];
    const float* as2 = (const float*)d_in[7];
    const float* ad2 = (const float*)d_in[8];
    const float* b2  = (const float*)d_in[9];
    float* out = (float*)d_out;

    const int N = in_sizes[0] / 256;
    const int E = in_sizes[1] / 2;
    const int* src = ei;
    const int* dst = ei + E;
    const int NBC = (N + CBSZ - 1) >> CBSH;     // coarse pairs buckets
    const int NG  = (N + GDS - 1) / GDS;        // gather blocks
    const int nchunk = (E + CH - 1) / CH;

    char* ws = (char*)d_ws;
    size_t off = 0;
    auto alloc = [&](size_t bytes) -> void* {
        void* p = ws + off;
        off = (off + bytes + 255) & ~(size_t)255;
        return p;
    };
    int*      bcur   = (int*)alloc((size_t)NBC * 4);
    unsigned* pairs  = (unsigned*)alloc((size_t)NBC * CAPC * 4);
    unsigned short* wt1 = (unsigned short*)alloc(64 * 256 * 2);
    unsigned short* wt2 = (unsigned short*)alloc(64 * 64 * 2);
    unsigned short* h1b = (unsigned short*)alloc((size_t)(N + 1) * 64 * 2);
    float* a_d1   = (float*)alloc((size_t)N * 8 * 4);
    unsigned short* gb  = (unsigned short*)alloc((size_t)(N + 1) * 64 * 2);
    float* a_d2   = (float*)alloc((size_t)N * 4);
    float* w2s    = (float*)alloc(64 * 4);
    float* w2d    = (float*)alloc(64 * 4);
    (void)ws_size; (void)n_in; (void)out_size;

    int prep_blocks = (20736 + NBC + 255) / 256;
    k_prep<<<prep_blocks, 256, 0, stream>>>(W1, W2, as2, ad2, wt1, wt2,
                                            h1b, gb, w2s, w2d, bcur, N, NBC);

    int gblk = (N + 63) / 64;
    k_mid<<<nchunk + gblk, 256, 0, stream>>>(src, dst, E, NBC, bcur, pairs,
                                             x, wt1, ad1, N, h1b, a_d1, nchunk);

    k_gather1f<<<NG, 256, 0, stream>>>(bcur, pairs, (const uint4*)h1b,
                                       a_d1, as1, b1, wt2, w2d,
                                       N, gb, a_d2);

    k_gather2<<<NG, 256, 0, stream>>>(bcur, pairs, (const uint4*)gb,
                                      a_d2, w2s, b2, N, out);
}

// Round 15
// 228.482 us; speedup vs baseline: 1.1089x; 1.1089x over previous
//
#include <hip/hip_runtime.h>
#include <math.h>

#define LRELU 0.2f
#define BSH 5                  // 32 dsts per bucket == one gather block
#define BSZ (1 << BSH)
#define CH 8192                // edges per binscat block
#define GB 10                  // gather batch depth (loads in flight per lane)
#define CAP 1408               // padded bucket capacity (avg ~1024, +12 sigma)
#define NBMAX 1600             // LDS histogram bins (>= NB = ceil(N/32))

typedef __attribute__((ext_vector_type(8))) short bf16x8;
typedef __attribute__((ext_vector_type(4))) float f32x4;

static __device__ __forceinline__ float bf2f(unsigned int u16) {
    union { unsigned int i; float f; } c; c.i = u16 << 16; return c.f;
}
static __device__ __forceinline__ unsigned short f2bf(float f) {
    union { float f; unsigned int i; } c; c.f = f;
    unsigned int x = c.i;
    return (unsigned short)((x + 0x7fffu + ((x >> 16) & 1u)) >> 16);  // RNE
}

// ---- prep: weight cvt + sentinels + w2 projections + padded-bucket init ----

__global__ __launch_bounds__(256) void k_prep(const float* __restrict__ W1,
                                              const float* __restrict__ W2,
                                              const float* __restrict__ as2in,
                                              const float* __restrict__ ad2in,
                                              unsigned short* __restrict__ Wt1,
                                              unsigned short* __restrict__ Wt2,
                                              unsigned short* __restrict__ h1b,
                                              unsigned short* __restrict__ gb,
                                              float* __restrict__ w2s,
                                              float* __restrict__ w2d,
                                              int* __restrict__ bcur,
                                              int N, int NB) {
    int idx = blockIdx.x * 256 + threadIdx.x;
    if (idx < 16384) {
        int n = idx >> 8, k = idx & 255;
        Wt1[idx] = f2bf(W1[k * 64 + n]);
    } else if (idx < 16384 + 4096) {
        int j = idx - 16384;
        int n = j >> 6, k = j & 63;
        Wt2[j] = f2bf(W2[k * 64 + n]);
    } else if (idx >= 20480 && idx < 20544) {
        h1b[(size_t)N * 64 + (idx - 20480)] = 0;           // Hb sentinel row = 0
    } else if (idx >= 20544 && idx < 20608) {
        gb[(size_t)N * 64 + (idx - 20544)] = 0;            // Gb sentinel row = 0
    } else if (idx >= 20608 && idx < 20672) {
        int c = idx - 20608;
        float s = 0.f;
#pragma unroll
        for (int n = 0; n < 64; ++n) s += W2[c * 64 + n] * as2in[n];
        w2s[c] = s;                                        // W2 @ att_src2
    } else if (idx >= 20672 && idx < 20736) {
        int c = idx - 20672;
        float s = 0.f;
#pragma unroll
        for (int n = 0; n < 64; ++n) s += W2[c * 64 + n] * ad2in[n];
        w2d[c] = s;                                        // W2 @ att_dst2
    } else if (idx >= 20736 && idx < 20736 + NB) {
        int b = idx - 20736;
        bcur[b] = b * CAP;                                 // padded bucket base
    }
}

// ---- mid: role-split fused kernel: binscat chunks (lds_d staged) + gemm1 ----
// lds_d overlays the gemm role's Xl buffer (both exactly 32 KB).

__global__ __launch_bounds__(256) void k_mid(const int* __restrict__ src,
                                             const int* __restrict__ dstArr,
                                             int E, int NB,
                                             int* __restrict__ bcur,
                                             unsigned* __restrict__ pairs,
                                             const float* __restrict__ X,
                                             const unsigned short* __restrict__ Wt,
                                             const float* __restrict__ attd,
                                             int N, unsigned short* __restrict__ Hb,
                                             float* __restrict__ adst,
                                             int nchunk) {
    __shared__ short Xl[64 * 256];          // 32 KB; binscat overlays lds_d here
    __shared__ int cnt2[NBMAX];             // 6.4 KB bucket histogram
    int t = threadIdx.x;
    if ((int)blockIdx.x < nchunk) {
        int* lds_d = (int*)Xl;              // CH ints = 32 KB, exact overlay
        int e0 = blockIdx.x * CH;
        int e1 = e0 + CH; if (e1 > E) e1 = E;
        int n = e1 - e0;
        for (int b = t; b < NBMAX; b += 256) cnt2[b] = 0;
        __syncthreads();
        for (int i = t; i < n; i += 256) {
            int d = dstArr[e0 + i];
            lds_d[i] = d;
            atomicAdd(&cnt2[d >> BSH], 1);
        }
        __syncthreads();
        for (int b = t; b < NB; b += 256) {
            int c = cnt2[b];
            cnt2[b] = c ? atomicAdd(&bcur[b], c) : 0;
        }
        __syncthreads();
        for (int i = t; i < n; i += 256) {
            int d = lds_d[i];
            int p = atomicAdd(&cnt2[d >> BSH], 1);
            pairs[p] = ((unsigned)src[e0 + i] << BSH) | (unsigned)(d & (BSZ - 1));
        }
        return;
    }
    // -------- gemm1 role --------
    int bx = (int)blockIdx.x - nchunk;
    int l = t & 63, w = t >> 6;
    int rblk = bx * 64;

    int half = l >> 5;
    int c8 = (l & 31) * 8;
#pragma unroll
    for (int i = 0; i < 8; ++i) {
        int rl = w * 16 + i * 2 + half;
        int row = rblk + rl;
        float4 x0 = {0.f, 0.f, 0.f, 0.f}, x1 = {0.f, 0.f, 0.f, 0.f};
        if (row < N) {
            x0 = *reinterpret_cast<const float4*>(X + (size_t)row * 256 + c8);
            x1 = *reinterpret_cast<const float4*>(X + (size_t)row * 256 + c8 + 4);
        }
        bf16x8 p;
        p[0] = (short)f2bf(x0.x); p[1] = (short)f2bf(x0.y);
        p[2] = (short)f2bf(x0.z); p[3] = (short)f2bf(x0.w);
        p[4] = (short)f2bf(x1.x); p[5] = (short)f2bf(x1.y);
        p[6] = (short)f2bf(x1.z); p[7] = (short)f2bf(x1.w);
        int g = (l & 31) ^ (rl & 7);
        *reinterpret_cast<bf16x8*>(&Xl[rl * 256 + g * 8]) = p;
    }
    __syncthreads();

    int m = l & 15, quad = l >> 4;
    int rl = w * 16 + m;
    f32x4 acc0 = {0.f, 0.f, 0.f, 0.f}, acc1 = acc0, acc2 = acc0, acc3 = acc0;
#pragma unroll
    for (int tt = 0; tt < 8; ++tt) {
        int g = (tt * 4 + quad) ^ (m & 7);
        bf16x8 a = *reinterpret_cast<const bf16x8*>(&Xl[rl * 256 + g * 8]);
        int kk = tt * 32 + quad * 8;
        bf16x8 b0 = *reinterpret_cast<const bf16x8*>(&Wt[(0 * 16 + m) * 256 + kk]);
        bf16x8 b1 = *reinterpret_cast<const bf16x8*>(&Wt[(1 * 16 + m) * 256 + kk]);
        bf16x8 b2 = *reinterpret_cast<const bf16x8*>(&Wt[(2 * 16 + m) * 256 + kk]);
        bf16x8 b3 = *reinterpret_cast<const bf16x8*>(&Wt[(3 * 16 + m) * 256 + kk]);
        acc0 = __builtin_amdgcn_mfma_f32_16x16x32_bf16(a, b0, acc0, 0, 0, 0);
        acc1 = __builtin_amdgcn_mfma_f32_16x16x32_bf16(a, b1, acc1, 0, 0, 0);
        acc2 = __builtin_amdgcn_mfma_f32_16x16x32_bf16(a, b2, acc2, 0, 0, 0);
        acc3 = __builtin_amdgcn_mfma_f32_16x16x32_bf16(a, b3, acc3, 0, 0, 0);
    }

    int r0 = rblk + w * 16;
    f32x4 accs[4] = {acc0, acc1, acc2, acc3};
#pragma unroll
    for (int nt = 0; nt < 4; ++nt) {
        int cn = nt * 16 + m;
        float av_d = attd[cn];
#pragma unroll
        for (int r = 0; r < 4; ++r) {
            int row = r0 + quad * 4 + r;
            float hv = accs[nt][r];
            if (row < N) Hb[(size_t)row * 64 + cn] = f2bf(hv);
            float vd = hv * av_d;
            vd += __shfl_xor(vd, 1, 64); vd += __shfl_xor(vd, 2, 64); vd += __shfl_xor(vd, 4, 64);
            if ((m & 7) == 0 && row < N) {
                adst[row * 8 + (cn >> 3)] = vd;
            }
        }
    }
}

// --- gather1 + in-LDS bucket sort + layer-2 GEMM fused. Block == bucket of
//     32 dsts. Stage pairs -> 32-bin counting sort in LDS -> per-group edge
//     loop reads sorted colT from LDS. One scattered line per edge. ---

__global__ __launch_bounds__(256) void k_gather1f(const int* __restrict__ bcur,
                                                  const unsigned* __restrict__ pairs,
                                                  const uint4* __restrict__ Hb8,
                                                  const float* __restrict__ adst,
                                                  const float* __restrict__ attS,
                                                  const float* __restrict__ bias,
                                                  const unsigned short* __restrict__ Wt2,
                                                  const float* __restrict__ w2d,
                                                  int N,
                                                  unsigned short* __restrict__ Gb,
                                                  float* __restrict__ ad2) {
    __shared__ int pairsS[CAP];
    __shared__ int colT[CAP];
    __shared__ int cntS[BSZ];
    __shared__ int baseS[BSZ];
    __shared__ int curS[BSZ];
    __shared__ short h2l[32 * 64];
    int t = threadIdx.x;
    int gid = t >> 3, sub = t & 7;
    int b = blockIdx.x;
    int d0 = b << BSH;
    int d = d0 + gid;
    int dok = (d < N);
    int dc = dok ? d : d0;
    float adv = dok ? adst[dc * 8 + sub] : 0.f;
    float aS[8];
#pragma unroll
    for (int c = 0; c < 8; ++c) aS[c] = attS[sub * 8 + c];

    // ---- in-LDS counting sort of this bucket ----
    int jb = b * CAP;
    int n = bcur[b] - jb;
    if (t < BSZ) cntS[t] = 0;
    __syncthreads();
    for (int i = t; i < n; i += 256) {
        int pk = (int)pairs[jb + i];
        pairsS[i] = pk;
        atomicAdd(&cntS[pk & (BSZ - 1)], 1);
    }
    __syncthreads();
    if (t < 64) {
        int v = (t < BSZ) ? cntS[t] : 0;
        int inc = v;
#pragma unroll
        for (int off = 1; off < BSZ; off <<= 1) {
            int q = __shfl_up(inc, off, 64);
            if (t >= off) inc += q;
        }
        if (t < BSZ) { baseS[t] = inc - v; curS[t] = inc - v; }
    }
    __syncthreads();
    for (int i = t; i < n; i += 256) {
        int pk = pairsS[i];
        int p = atomicAdd(&curS[pk & (BSZ - 1)], 1);
        colT[p] = pk >> BSH;
    }
    __syncthreads();

    int lo = baseS[gid];
    int hi = lo + cntS[gid];

    float acc[8] = {0.f, 0.f, 0.f, 0.f, 0.f, 0.f, 0.f, 0.f};
    float denom = 0.f;
    for (int u = lo; u < hi; u += GB) {
        uint4 hv8[GB];
#pragma unroll
        for (int q = 0; q < GB; ++q) {
            int uu = u + q;
            int s = (uu < hi) ? colT[uu] : N;   // sentinel row = 0
            hv8[q] = Hb8[(size_t)s * 8 + sub];
        }
        __builtin_amdgcn_sched_barrier(0);
#pragma unroll
        for (int q = 0; q < GB; ++q) {
            uint4 hv = hv8[q];
            float f0 = bf2f(hv.x & 0xffffu), f1 = bf2f(hv.x >> 16);
            float f2 = bf2f(hv.y & 0xffffu), f3 = bf2f(hv.y >> 16);
            float f4 = bf2f(hv.z & 0xffffu), f5 = bf2f(hv.z >> 16);
            float f6 = bf2f(hv.w & 0xffffu), f7 = bf2f(hv.w >> 16);
            float ps = f0 * aS[0];
            ps = fmaf(f1, aS[1], ps); ps = fmaf(f2, aS[2], ps);
            ps = fmaf(f3, aS[3], ps); ps = fmaf(f4, aS[4], ps);
            ps = fmaf(f5, aS[5], ps); ps = fmaf(f6, aS[6], ps);
            ps = fmaf(f7, aS[7], ps);
            float e = ps + adv;
            e = (e > 0.f) ? e : LRELU * e;
            float wgt = ((u + q) < hi) ? __expf(e) : 0.f;
            denom += wgt;
            acc[0] = fmaf(wgt, f0, acc[0]); acc[1] = fmaf(wgt, f1, acc[1]);
            acc[2] = fmaf(wgt, f2, acc[2]); acc[3] = fmaf(wgt, f3, acc[3]);
            acc[4] = fmaf(wgt, f4, acc[4]); acc[5] = fmaf(wgt, f5, acc[5]);
            acc[6] = fmaf(wgt, f6, acc[6]); acc[7] = fmaf(wgt, f7, acc[7]);
        }
    }

    // h2 = elu(agg/denom + bias1); ad2 = h2 . (W2@att_dst2) group-reduced
    float invd = 1.f / (denom + 1e-16f);
    float v[8];
#pragma unroll
    for (int c = 0; c < 8; ++c) {
        float x = fmaf(acc[c], invd, bias[sub * 8 + c]);
        v[c] = (x > 0.f) ? x : expm1f(x);
    }
    float vd = 0.f;
#pragma unroll
    for (int c = 0; c < 8; ++c) vd = fmaf(v[c], w2d[sub * 8 + c], vd);
    vd += __shfl_xor(vd, 1, 64); vd += __shfl_xor(vd, 2, 64); vd += __shfl_xor(vd, 4, 64);
    if (dok && sub == 0) ad2[d] = vd;

    // stage h2 bf16 into LDS, octet XOR-swizzled (row r, octet o at o^(r&7))
    bf16x8 p;
#pragma unroll
    for (int c = 0; c < 8; ++c) p[c] = (short)f2bf(v[c]);
    *reinterpret_cast<bf16x8*>(&h2l[gid * 64 + (sub ^ (gid & 7)) * 8]) = p;
    __syncthreads();

    // 32x64 = h2l(32x64) @ W2(64x64), 16x16x32 MFMA, 4 waves x (1 Mtile x 2 Ntiles)
    int l = t & 63, w = t >> 6;
    int m = l & 15, quad = l >> 4;
    int mt = w & 1;
    int ntb = (w >> 1) * 2;
    int r = mt * 16 + m;
    f32x4 g0 = {0.f, 0.f, 0.f, 0.f}, g1 = g0;
#pragma unroll
    for (int tt = 0; tt < 2; ++tt) {
        bf16x8 a = *reinterpret_cast<const bf16x8*>(
            &h2l[r * 64 + ((tt * 4 + quad) ^ (r & 7)) * 8]);
        int kk = tt * 32 + quad * 8;
        bf16x8 b0 = *reinterpret_cast<const bf16x8*>(&Wt2[((ntb + 0) * 16 + m) * 64 + kk]);
        bf16x8 b1 = *reinterpret_cast<const bf16x8*>(&Wt2[((ntb + 1) * 16 + m) * 64 + kk]);
        g0 = __builtin_amdgcn_mfma_f32_16x16x32_bf16(a, b0, g0, 0, 0, 0);
        g1 = __builtin_amdgcn_mfma_f32_16x16x32_bf16(a, b1, g1, 0, 0, 0);
    }
    f32x4 gs[2] = {g0, g1};
#pragma unroll
    for (int nt = 0; nt < 2; ++nt) {
        int cn = (ntb + nt) * 16 + m;
#pragma unroll
        for (int rr = 0; rr < 4; ++rr) {
            int dr = d0 + mt * 16 + quad * 4 + rr;
            if (dr < N) Gb[(size_t)dr * 64 + cn] = f2bf(gs[nt][rr]);
        }
    }
}

// --- gather2: same in-LDS sort; asrc2 derived from the Gb row ---

__global__ __launch_bounds__(256) void k_gather2(const int* __restrict__ bcur,
                                                 const unsigned* __restrict__ pairs,
                                                 const uint4* __restrict__ Gb8,
                                                 const float* __restrict__ adst,
                                                 const float* __restrict__ w2s,
                                                 const float* __restrict__ bias,
                                                 int N,
                                                 float* __restrict__ out) {
    __shared__ int pairsS[CAP];
    __shared__ int colT[CAP];
    __shared__ int cntS[BSZ];
    __shared__ int baseS[BSZ];
    __shared__ int curS[BSZ];
    int t = threadIdx.x;
    int gid = t >> 3, sub = t & 7;
    int b = blockIdx.x;
    int d0 = b << BSH;
    int d = d0 + gid;
    int dok = (d < N);
    int dc = dok ? d : d0;
    float adv = dok ? adst[dc] : 0.f;
    float wS[8];
#pragma unroll
    for (int c = 0; c < 8; ++c) wS[c] = w2s[sub * 8 + c];

    int jb = b * CAP;
    int n = bcur[b] - jb;
    if (t < BSZ) cntS[t] = 0;
    __syncthreads();
    for (int i = t; i < n; i += 256) {
        int pk = (int)pairs[jb + i];
        pairsS[i] = pk;
        atomicAdd(&cntS[pk & (BSZ - 1)], 1);
    }
    __syncthreads();
    if (t < 64) {
        int v = (t < BSZ) ? cntS[t] : 0;
        int inc = v;
#pragma unroll
        for (int off = 1; off < BSZ; off <<= 1) {
            int q = __shfl_up(inc, off, 64);
            if (t >= off) inc += q;
        }
        if (t < BSZ) { baseS[t] = inc - v; curS[t] = inc - v; }
    }
    __syncthreads();
    for (int i = t; i < n; i += 256) {
        int pk = pairsS[i];
        int p = atomicAdd(&curS[pk & (BSZ - 1)], 1);
        colT[p] = pk >> BSH;
    }
    __syncthreads();

    int lo = baseS[gid];
    int hi = lo + cntS[gid];

    float acc[8] = {0.f, 0.f, 0.f, 0.f, 0.f, 0.f, 0.f, 0.f};
    float denom = 0.f;
    for (int u = lo; u < hi; u += GB) {
        uint4 hv8[GB];
#pragma unroll
        for (int q = 0; q < GB; ++q) {
            int uu = u + q;
            int s = (uu < hi) ? colT[uu] : N;
            hv8[q] = Gb8[(size_t)s * 8 + sub];
        }
        __builtin_amdgcn_sched_barrier(0);
#pragma unroll
        for (int q = 0; q < GB; ++q) {
            uint4 hv = hv8[q];
            float f0 = bf2f(hv.x & 0xffffu), f1 = bf2f(hv.x >> 16);
            float f2 = bf2f(hv.y & 0xffffu), f3 = bf2f(hv.y >> 16);
            float f4 = bf2f(hv.z & 0xffffu), f5 = bf2f(hv.z >> 16);
            float f6 = bf2f(hv.w & 0xffffu), f7 = bf2f(hv.w >> 16);
            float ps = f0 * wS[0];
            ps = fmaf(f1, wS[1], ps); ps = fmaf(f2, wS[2], ps);
            ps = fmaf(f3, wS[3], ps); ps = fmaf(f4, wS[4], ps);
            ps = fmaf(f5, wS[5], ps); ps = fmaf(f6, wS[6], ps);
            ps = fmaf(f7, wS[7], ps);
            ps += __shfl_xor(ps, 1, 64);
            ps += __shfl_xor(ps, 2, 64);
            ps += __shfl_xor(ps, 4, 64);
            float e = ps + adv;
            e = (e > 0.f) ? e : LRELU * e;
            float wgt = ((u + q) < hi) ? __expf(e) : 0.f;
            denom += wgt;
            acc[0] = fmaf(wgt, f0, acc[0]); acc[1] = fmaf(wgt, f1, acc[1]);
            acc[2] = fmaf(wgt, f2, acc[2]); acc[3] = fmaf(wgt, f3, acc[3]);
            acc[4] = fmaf(wgt, f4, acc[4]); acc[5] = fmaf(wgt, f5, acc[5]);
            acc[6] = fmaf(wgt, f6, acc[6]); acc[7] = fmaf(wgt, f7, acc[7]);
        }
    }
    float invd = 1.f / (denom + 1e-16f);
    float v[8];
#pragma unroll
    for (int c = 0; c < 8; ++c) v[c] = fmaf(acc[c], invd, bias[sub * 8 + c]);
    // log_softmax over the 8-lane group (64 channels per dst)
    float m = v[0];
#pragma unroll
    for (int c = 1; c < 8; ++c) m = fmaxf(m, v[c]);
    m = fmaxf(m, __shfl_xor(m, 1, 64));
    m = fmaxf(m, __shfl_xor(m, 2, 64));
    m = fmaxf(m, __shfl_xor(m, 4, 64));
    float se = 0.f;
#pragma unroll
    for (int c = 0; c < 8; ++c) se += __expf(v[c] - m);
    se += __shfl_xor(se, 1, 64);
    se += __shfl_xor(se, 2, 64);
    se += __shfl_xor(se, 4, 64);
    float ls = m + __logf(se);
    if (dok) {
        float4 o0, o1;
        o0.x = v[0] - ls; o0.y = v[1] - ls; o0.z = v[2] - ls; o0.w = v[3] - ls;
        o1.x = v[4] - ls; o1.y = v[5] - ls; o1.z = v[6] - ls; o1.w = v[7] - ls;
        *reinterpret_cast<float4*>(&out[(size_t)d * 64 + sub * 8]) = o0;
        *reinterpret_cast<float4*>(&out[(size_t)d * 64 + sub * 8 + 4]) = o1;
    }
}

// ---------------- launch ----------------

extern "C" void kernel_launch(void* const* d_in, const int* in_sizes, int n_in,
                              void* d_out, int out_size, void* d_ws, size_t ws_size,
                              hipStream_t stream) {
    const float* x   = (const float*)d_in[0];
    const int*   ei  = (const int*)d_in[1];
    const float* W1  = (const float*)d_in[2];
    const float* as1 = (const float*)d_in[3];
    const float* ad1 = (const float*)d_in[4];
    const float* b1  = (const float*)d_in[5];
    const float* W2  = (const float*)d_in[6];
    const float* as2 = (const float*)d_in[7];
    const float* ad2 = (const float*)d_in[8];
    const float* b2  = (const float*)d_in[9];
    float* out = (float*)d_out;

    const int N = in_sizes[0] / 256;
    const int E = in_sizes[1] / 2;
    const int* src = ei;
    const int* dst = ei + E;
    const int NB = (N + BSZ - 1) >> BSH;
    const int nchunk = (E + CH - 1) / CH;

    char* ws = (char*)d_ws;
    size_t off = 0;
    auto alloc = [&](size_t bytes) -> void* {
        void* p = ws + off;
        off = (off + bytes + 255) & ~(size_t)255;
        return p;
    };
    int*      bcur   = (int*)alloc((size_t)NB * 4);
    unsigned* pairs  = (unsigned*)alloc((size_t)NB * CAP * 4);
    unsigned short* wt1 = (unsigned short*)alloc(64 * 256 * 2);
    unsigned short* wt2 = (unsigned short*)alloc(64 * 64 * 2);
    unsigned short* h1b = (unsigned short*)alloc((size_t)(N + 1) * 64 * 2);
    float* a_d1   = (float*)alloc((size_t)N * 8 * 4);
    unsigned short* gb  = (unsigned short*)alloc((size_t)(N + 1) * 64 * 2);
    float* a_d2   = (float*)alloc((size_t)N * 4);
    float* w2s    = (float*)alloc(64 * 4);
    float* w2d    = (float*)alloc(64 * 4);
    (void)ws_size; (void)n_in; (void)out_size;

    int prep_blocks = (20736 + NB + 255) / 256;
    k_prep<<<prep_blocks, 256, 0, stream>>>(W1, W2, as2, ad2, wt1, wt2,
                                            h1b, gb, w2s, w2d, bcur, N, NB);

    int gblk = (N + 63) / 64;
    k_mid<<<nchunk + gblk, 256, 0, stream>>>(src, dst, E, NB, bcur, pairs,
                                             x, wt1, ad1, N, h1b, a_d1, nchunk);

    k_gather1f<<<NB, 256, 0, stream>>>(bcur, pairs, (const uint4*)h1b,
                                       a_d1, as1, b1, wt2, w2d,
                                       N, gb, a_d2);

    k_gather2<<<NB, 256, 0, stream>>>(bcur, pairs, (const uint4*)gb,
                                      a_d2, w2s, b2, N, out);
}